// Round 22
// baseline (58.942 us; speedup 1.0000x reference)
//
#include <hip/hip_runtime.h>
#include <math.h>

#define S_LEN  2048
#define D_HEAD 128
#define QBLK   64
#define KVBLK  64
#define BATCH  16
#define NKVT   (S_LEN / KVBLK)     // 32 kv tiles per batch
#define TILE_SH 8192               // shorts per 64x128 tile image (16 KB)
#define SLOTS_PB 56                // partial slots per batch: 16 qb x2 + 8 qb x3

typedef __attribute__((ext_vector_type(4))) float f32x4;
typedef __attribute__((ext_vector_type(8))) short short8;

__device__ __forceinline__ unsigned short f2bf(float x) {
    union { float f; unsigned u; } v; v.f = x;
    unsigned r = v.u + 0x7fffu + ((v.u >> 16) & 1u);
    return (unsigned short)(r >> 16);
}
__device__ __forceinline__ float bf2f(unsigned short h) {
    union { unsigned u; float f; } v; v.u = ((unsigned)h) << 16;
    return v.f;
}
__device__ __forceinline__ unsigned pack2(unsigned short a, unsigned short b) {
    return (unsigned)a | ((unsigned)b << 16);
}
__device__ __forceinline__ unsigned cvtpk(float lo, float hi) {
    unsigned r;
    asm("v_cvt_pk_bf16_f32 %0, %1, %2" : "=v"(r) : "v"(lo), "v"(hi));
    return r;
}
__device__ __forceinline__ void gld16(const void* g, void* l) {
    __builtin_amdgcn_global_load_lds(
        (const __attribute__((address_space(1))) void*)g,
        (__attribute__((address_space(3))) void*)l, 16, 0, 0);
}
template<int N> __device__ __forceinline__ void wait_vm() {
    asm volatile("s_waitcnt vmcnt(%0)" :: "i"(N) : "memory");
}
__device__ __forceinline__ void barrier() {
    __builtin_amdgcn_sched_barrier(0);
    __builtin_amdgcn_s_barrier();
    __builtin_amdgcn_sched_barrier(0);
}
__device__ __forceinline__ int slot_base(int b, int qb) {   // qb >= 8
    return b * SLOTS_PB + ((qb >= 24) ? (32 + (qb - 24) * 3) : ((qb - 8) * 2));
}

// prep: one block per (batch, kv-tile). Emits PRE-SWIZZLED contiguous LDS images.
__global__ __launch_bounds__(256) void prep(const float* __restrict__ K,
                                            const float* __restrict__ V,
                                            unsigned short* __restrict__ Kp,
                                            unsigned short* __restrict__ Vp)
{
    const int tid = threadIdx.x;
    const int bid = blockIdx.x;
    const int b = bid >> 5, t = bid & 31;
    const size_t ibase = (size_t)b * S_LEN * D_HEAD + (size_t)t * KVBLK * D_HEAD;
    unsigned short* ko = Kp + (size_t)bid * TILE_SH;
    unsigned short* vo = Vp + (size_t)bid * TILE_SH;

    #pragma unroll
    for (int c = 0; c < 4; ++c) {
        int i  = c * 256 + tid;
        int k  = i >> 4;
        int d8 = ((i & 15) * 8) ^ ((k & 7) << 3);
        const float* sp = K + ibase + (size_t)k * D_HEAD + d8;
        float4 a = *(const float4*)sp;
        float4 bb = *(const float4*)(sp + 4);
        uint4 u = { pack2(f2bf(a.x),f2bf(a.y)),  pack2(f2bf(a.z),f2bf(a.w)),
                    pack2(f2bf(bb.x),f2bf(bb.y)),pack2(f2bf(bb.z),f2bf(bb.w)) };
        *(uint4*)(ko + i * 8) = u;
    }

    __shared__ unsigned short Vb[KVBLK][D_HEAD + 2];
    {
        const int r  = tid >> 2;
        const int c0 = (tid & 3) * 32;
        const float* sp = V + ibase + (size_t)r * D_HEAD + c0;
        #pragma unroll
        for (int i = 0; i < 8; ++i) {
            float4 x = *(const float4*)(sp + i * 4);
            Vb[r][c0+i*4+0] = f2bf(x.x); Vb[r][c0+i*4+1] = f2bf(x.y);
            Vb[r][c0+i*4+2] = f2bf(x.z); Vb[r][c0+i*4+3] = f2bf(x.w);
        }
    }
    __syncthreads();
    #pragma unroll
    for (int c = 0; c < 4; ++c) {
        int i   = c * 256 + tid;
        int d   = i >> 3;
        int kk0 = ((i & 7) * 8) ^ ((d & 7) << 3);
        unsigned short h[8];
        #pragma unroll
        for (int j = 0; j < 8; ++j) h[j] = Vb[kk0 + j][d];
        uint4 u = { pack2(h[0],h[1]), pack2(h[2],h[3]), pack2(h[4],h[5]), pack2(h[6],h[7]) };
        *(uint4*)(vo + i * 8) = u;
    }
}

// MODE 1: 1024 jobs, bid = o*16 + b (XCD = b%8; 2 batches/XCD). Schedule as
// r11/r15 (4 size-flat rounds, 33 visits/CU). Partials merged by a SEPARATE
// combine kernel (fused merges failed twice: r10/r12).
//
// 2-barrier loop. Hazard ledger:
//   bar1 (top):  all waves past prev PV -> Vlds free for stage_V(t);
//                preceded by per-wave vm0 -> own K(t) issues landed; bar1
//                broadcasts "all K(t) quarters landed".
//   bar2 (mid):  preceded by per-wave vm0 -> own V(t) issues landed; bar2
//                broadcasts "all V(t) quarters landed" AND "all waves done
//                reading Klds (QK^T)" -> stage_K(t+1) safe after bar2.
//   P-write:     HOISTED above bar2 (wave-private Plds; PV's read-after-write
//                is covered by in-wave ds ordering) -> ds_writes complete
//                during barrier-arrival skew, shortening the post-bar2 chain.
template<int MODE>
__global__ __launch_bounds__(256, 4)
void attn_fwd(const float* __restrict__ Qg, const unsigned short* __restrict__ Kp,
              const unsigned short* __restrict__ Vp, float* __restrict__ Og,
              unsigned short* __restrict__ Po, float* __restrict__ Ml)
{
    constexpr float CSC = 0.12751744f;      // log2(e)/sqrt(128), folded into Q
    const int tid  = threadIdx.x;
    const int lane = tid & 63;
    const int w    = tid >> 6;
    const int bid  = blockIdx.x;

    int b, qb, lo, nt, C = 1, piece = 0, pslot = -1;
    if (MODE == 0) {
        b = bid & 15;
        const int rank = bid >> 4;
        qb = (rank < 16) ? (31 - rank) : (rank - 16);
        lo = 0; nt = qb + 1;
    } else {
        b = bid & 15;
        const int o = bid >> 4, k = o & 15, r = o >> 4;
        if (r <= 1)      { qb = 31 - k; C = (k < 8) ? 3 : 2; piece = r; }
        else if (r == 2) { if (k < 8) { qb = 31 - k; C = 3; piece = 2; }
                           else       { qb = k;      C = 2; piece = 0; } }
        else             { if (k < 8) { qb = k;      C = 1; piece = 0; }
                           else       { qb = k;      C = 2; piece = 1; } }
        const int n = qb + 1, q_ = n / C, rem = n % C;
        lo = piece * q_ + min(piece, rem);
        nt = q_ + (piece < rem ? 1 : 0);
        if (C > 1) pslot = slot_base(b, qb) + piece;
    }
    const int q0w  = qb * QBLK + w * 16;
    const int qc   = lane & 15;
    const int g    = lane >> 4;
    const int qidx = q0w + qc;

    __shared__ __align__(16) unsigned short Klds[TILE_SH];        // 16 KB
    __shared__ __align__(16) unsigned short Vlds[TILE_SH];        // 16 KB
    __shared__ __align__(16) unsigned short Plds[4][16 * KVBLK];  //  8 KB

    const size_t base = (size_t)b * S_LEN * D_HEAD;
    const int tb = b * NKVT;

    auto stage_K = [&](int t) {             // 4 DMA issues/wave
        const unsigned short* ks = Kp + (size_t)(tb + t) * TILE_SH + w * 2048 + lane * 8;
        #pragma unroll
        for (int ii = 0; ii < 4; ++ii) gld16(ks + ii * 512, &Klds[w * 2048 + ii * 512]);
    };
    auto stage_V = [&](int t) {
        const unsigned short* vs = Vp + (size_t)(tb + t) * TILE_SH + w * 2048 + lane * 8;
        #pragma unroll
        for (int ii = 0; ii < 4; ++ii) gld16(vs + ii * 512, &Vlds[w * 2048 + ii * 512]);
    };

    // ---- Q fragments (MFMA B operand), pre-scaled ----
    short8 qf[4];
    {
        const float* qp = Qg + base + (size_t)(q0w + qc) * D_HEAD + g * 8;
        #pragma unroll
        for (int db = 0; db < 4; ++db) {
            float4 x0 = *(const float4*)(qp + db * 32);
            float4 x1 = *(const float4*)(qp + db * 32 + 4);
            float tt[8] = {x0.x, x0.y, x0.z, x0.w, x1.x, x1.y, x1.z, x1.w};
            short8 f;
            #pragma unroll
            for (int jj = 0; jj < 8; ++jj) f[jj] = (short)f2bf(tt[jj] * CSC);
            qf[db] = f;
        }
    }

    f32x4 acc[8] = {};                      // acc[db][r] = O[q=4g+r][d=db*16+qc]
    float m = -1e30f, lsum = 0.f;           // lsum lane-partial until epilogue

    stage_K(lo);                            // K(lo) in flight over Q-frag load

    for (int i = 0; i < nt; ++i) {
        const int t   = lo + i;
        const int kv0 = t * KVBLK;
        const bool more = (i + 1 < nt);

        // bar1: own K(t) landed (vm0) + all waves past prev PV -> Vlds free
        wait_vm<0>();
        barrier();
        stage_V(t);                          // V(t) DMA hides under QK^T+softmax

        const int t16max = min(3, (q0w + 15 - kv0) >> 4);
        const int ksmax  = min(1, (q0w + 15 - kv0) >> 5);

        // ---- swapped QK^T: rows = k, cols = q ----
        f32x4 st[4] = {};
        __builtin_amdgcn_s_setprio(1);
        #pragma unroll
        for (int t16 = 0; t16 < 4; ++t16) {
            if (t16 <= t16max) {
                const int kr = t16 * 16 + qc;
                const int swz = (kr & 7) << 3;
                #pragma unroll
                for (int db = 0; db < 4; ++db) {
                    short8 kf = *(const short8*)&Klds[(kr * 128 + db * 32 + g * 8) ^ swz];
                    st[t16] = __builtin_amdgcn_mfma_f32_16x16x32_bf16(kf, qf[db], st[t16], 0, 0, 0);
                }
            }
        }
        __builtin_amdgcn_s_setprio(0);

        float s[16];
        #pragma unroll
        for (int t16 = 0; t16 < 4; ++t16)
            #pragma unroll
            for (int r = 0; r < 4; ++r)
                s[t16*4+r] = (t16 <= t16max) ? st[t16][r] : -1e30f;

        if (kv0 + KVBLK - 1 > q0w) {         // diagonal: per-lane causal mask
            #pragma unroll
            for (int t16 = 0; t16 < 4; ++t16)
                #pragma unroll
                for (int r = 0; r < 4; ++r)
                    if (kv0 + t16 * 16 + g * 4 + r > qidx) s[t16*4+r] = -1e30f;
        }

        // ---- online softmax, defer-max; no cross-lane ops in common path ----
        float m0 = fmaxf(fmaxf(s[0],s[1]), fmaxf(s[2],s[3]));
        float m1 = fmaxf(fmaxf(s[4],s[5]), fmaxf(s[6],s[7]));
        float m2 = fmaxf(fmaxf(s[8],s[9]), fmaxf(s[10],s[11]));
        float m3 = fmaxf(fmaxf(s[12],s[13]), fmaxf(s[14],s[15]));
        float mx = fmaxf(fmaxf(m0,m1), fmaxf(m2,m3));

        if (__any(mx > m + 8.0f)) {
            mx = fmaxf(mx, __shfl_xor(mx, 16));
            mx = fmaxf(mx, __shfl_xor(mx, 32));
            float mnew = fmaxf(m, mx);
            float alpha = exp2f(m - mnew);
            m = mnew;
            lsum *= alpha;
            float a_o[4];
            #pragma unroll
            for (int r = 0; r < 4; ++r) a_o[r] = __shfl(alpha, g * 4 + r);
            #pragma unroll
            for (int db = 0; db < 8; ++db)
                #pragma unroll
                for (int r = 0; r < 4; ++r) acc[db][r] *= a_o[r];
        }

        float p16[16];
        #pragma unroll
        for (int ii = 0; ii < 16; ++ii) p16[ii] = exp2f(s[ii] - m);
        float r0 = (p16[0]+p16[1]) + (p16[2]+p16[3]);
        float r1 = (p16[4]+p16[5]) + (p16[6]+p16[7]);
        float r2 = (p16[8]+p16[9]) + (p16[10]+p16[11]);
        float r3 = (p16[12]+p16[13]) + (p16[14]+p16[15]);
        lsum += (r0+r1) + (r2+r3);

        // ---- P -> wave-private LDS (bf16, swizzled) — hoisted above bar2 ----
        const int pswz = (qc & 7) << 3;
        #pragma unroll
        for (int t16 = 0; t16 < 4; ++t16) {
            uint2 uu = { cvtpk(p16[t16*4+0], p16[t16*4+1]), cvtpk(p16[t16*4+2], p16[t16*4+3]) };
            *(uint2*)&Plds[w][(qc * 64 + t16 * 16 + g * 4) ^ pswz] = uu;
        }

        // bar2: own V(t) landed (vm0) + all waves done reading Klds
        wait_vm<0>();
        barrier();
        if (more) stage_K(t + 1);            // K DMA hides under PV

        // ---- PV ----
        __builtin_amdgcn_s_setprio(1);
        #pragma unroll
        for (int ks = 0; ks < 2; ++ks) {
            if (ks <= ksmax) {
                short8 pa = *(const short8*)&Plds[w][(qc * 64 + ks * 32 + g * 8) ^ pswz];
                #pragma unroll
                for (int db = 0; db < 8; ++db) {
                    const int d = db * 16 + qc;
                    short8 vf = *(const short8*)&Vlds[(d * 64 + ks * 32 + g * 8) ^ ((d & 7) << 3)];
                    acc[db] = __builtin_amdgcn_mfma_f32_16x16x32_bf16(pa, vf, acc[db], 0, 0, 0);
                }
            }
        }
        __builtin_amdgcn_s_setprio(0);
        // no post-PV barrier: next iteration's bar1 protects Vlds
    }

    // ---- epilogue ----
    lsum += __shfl_xor(lsum, 16);
    lsum += __shfl_xor(lsum, 32);

    if (pslot < 0) {                         // direct write (C==1 or MODE 0)
        float linv = 1.0f / lsum;
        float li[4];
        #pragma unroll
        for (int r = 0; r < 4; ++r) li[r] = __shfl(linv, g * 4 + r);
        #pragma unroll
        for (int db = 0; db < 8; ++db)
            #pragma unroll
            for (int r = 0; r < 4; ++r)
                Og[base + (size_t)(q0w + g * 4 + r) * D_HEAD + db * 16 + qc] = acc[db][r] * li[r];
    } else {                                 // bf16 partial + (m,l)
        unsigned short* po = Po + (size_t)pslot * (QBLK * D_HEAD);
        #pragma unroll
        for (int db = 0; db < 8; ++db)
            #pragma unroll
            for (int r = 0; r < 4; ++r)
                po[(w * 16 + g * 4 + r) * D_HEAD + db * 16 + qc] = f2bf(acc[db][r]);
        if (g == 0) {
            float* ml = Ml + (size_t)pslot * (QBLK * 2);
            ml[(w * 16 + qc) * 2 + 0] = m;
            ml[(w * 16 + qc) * 2 + 1] = lsum;
        }
    }
}

// combine C in {2,3} pieces of each split q-block (qb 8..31); 384 blocks.
__global__ __launch_bounds__(256)
void combine(const unsigned short* __restrict__ Po, const float* __restrict__ Ml,
             float* __restrict__ Og)
{
    const int z   = blockIdx.x;             // j*16 + b  (XCD = b%8)
    const int b   = z & 15;
    const int j   = z >> 4;                 // 0..23
    const int qb  = (j < 16) ? (8 + j) : (24 + (j - 16));
    const int C   = (qb >= 24) ? 3 : 2;
    const int tid = threadIdx.x;
    const int row = tid >> 2;
    const int c0  = (tid & 3) * 32;
    const int sb  = slot_base(b, qb);

    float mm[3], lv[3], M = -1e30f;
    #pragma unroll
    for (int c = 0; c < 3; ++c) {
        if (c < C) {
            const float* ml = Ml + (size_t)(sb + c) * (QBLK * 2);
            mm[c] = ml[row * 2 + 0];
            lv[c] = ml[row * 2 + 1];
            M = fmaxf(M, mm[c]);
        }
    }
    float den = 0.f, wgt[3];
    #pragma unroll
    for (int c = 0; c < 3; ++c) {
        if (c < C) { wgt[c] = exp2f(mm[c] - M); den += wgt[c] * lv[c]; }
    }
    const float rd = 1.0f / den;

    float am[32];
    #pragma unroll
    for (int q = 0; q < 32; ++q) am[q] = 0.f;
    #pragma unroll
    for (int c = 0; c < 3; ++c) {
        if (c < C) {
            const unsigned short* po = Po + (size_t)(sb + c) * (QBLK * D_HEAD) + row * D_HEAD + c0;
            const float wc = wgt[c];
            #pragma unroll
            for (int q = 0; q < 4; ++q) {
                uint4 u = *(const uint4*)(po + q * 8);
                const unsigned short* h = (const unsigned short*)&u;
                #pragma unroll
                for (int e = 0; e < 8; ++e) am[q * 8 + e] += wc * bf2f(h[e]);
            }
        }
    }
    float* op = Og + (size_t)b * S_LEN * D_HEAD + (size_t)(qb * QBLK + row) * D_HEAD + c0;
    #pragma unroll
    for (int q = 0; q < 8; ++q) {
        float4 r = { am[q*4+0] * rd, am[q*4+1] * rd, am[q*4+2] * rd, am[q*4+3] * rd };
        *(float4*)(op + q * 4) = r;
    }
}

extern "C" void kernel_launch(void* const* d_in, const int* in_sizes, int n_in,
                              void* d_out, int out_size, void* d_ws, size_t ws_size,
                              hipStream_t stream) {
    const float* Q = (const float*)d_in[0];
    const float* K = (const float*)d_in[1];
    const float* V = (const float*)d_in[2];
    float* O = (float*)d_out;

    const size_t tile_elems = (size_t)BATCH * NKVT * TILE_SH;       // 4.19M shorts each
    const size_t nslots = (size_t)BATCH * SLOTS_PB;                 // 896
    unsigned short* Kp = (unsigned short*)d_ws;
    unsigned short* Vp = Kp + tile_elems;
    unsigned short* Po = Vp + tile_elems;                           // 896 x 8192 bf16
    float*          Mlp = (float*)(Po + nslots * QBLK * D_HEAD);    // 896 x 128 f32
    const size_t need_bytes = (char*)(Mlp + nslots * QBLK * 2) - (char*)d_ws;

    prep<<<dim3(BATCH * NKVT), dim3(256), 0, stream>>>(K, V, Kp, Vp);
    if (ws_size >= need_bytes) {
        attn_fwd<1><<<dim3(1024), dim3(256), 0, stream>>>(Q, Kp, Vp, O, Po, Mlp);
        combine<<<dim3(24 * BATCH), dim3(256), 0, stream>>>(Po, Mlp, O);
    } else {
        attn_fwd<0><<<dim3(512), dim3(256), 0, stream>>>(Q, Kp, Vp, O, nullptr, nullptr);
    }
}

// Round 23
// 58.232 us; speedup vs baseline: 1.0122x; 1.0122x over previous
//
#include <hip/hip_runtime.h>
#include <math.h>

#define S_LEN  2048
#define D_HEAD 128
#define QBLK   64
#define KVBLK  64
#define BATCH  16
#define NKVT   (S_LEN / KVBLK)     // 32 kv tiles per batch
#define TILE_SH 8192               // shorts per 64x128 tile image (16 KB)
#define SLOTS_PB 56                // partial slots per batch: 16 qb x2 + 8 qb x3

typedef __attribute__((ext_vector_type(4))) float f32x4;
typedef __attribute__((ext_vector_type(8))) short short8;

__device__ __forceinline__ unsigned short f2bf(float x) {
    union { float f; unsigned u; } v; v.f = x;
    unsigned r = v.u + 0x7fffu + ((v.u >> 16) & 1u);
    return (unsigned short)(r >> 16);
}
__device__ __forceinline__ float bf2f(unsigned short h) {
    union { unsigned u; float f; } v; v.u = ((unsigned)h) << 16;
    return v.f;
}
__device__ __forceinline__ unsigned pack2(unsigned short a, unsigned short b) {
    return (unsigned)a | ((unsigned)b << 16);
}
__device__ __forceinline__ unsigned cvtpk(float lo, float hi) {
    unsigned r;
    asm("v_cvt_pk_bf16_f32 %0, %1, %2" : "=v"(r) : "v"(lo), "v"(hi));
    return r;
}
__device__ __forceinline__ void gld16(const void* g, void* l) {
    __builtin_amdgcn_global_load_lds(
        (const __attribute__((address_space(1))) void*)g,
        (__attribute__((address_space(3))) void*)l, 16, 0, 0);
}
template<int N> __device__ __forceinline__ void wait_vm() {
    asm volatile("s_waitcnt vmcnt(%0)" :: "i"(N) : "memory");
}
__device__ __forceinline__ void barrier() {
    __builtin_amdgcn_sched_barrier(0);
    __builtin_amdgcn_s_barrier();
    __builtin_amdgcn_sched_barrier(0);
}
__device__ __forceinline__ int slot_base(int b, int qb) {   // qb >= 8
    return b * SLOTS_PB + ((qb >= 24) ? (32 + (qb - 24) * 3) : ((qb - 8) * 2));
}

// prep: one block per (batch, kv-tile). Emits PRE-SWIZZLED contiguous LDS images.
__global__ __launch_bounds__(256) void prep(const float* __restrict__ K,
                                            const float* __restrict__ V,
                                            unsigned short* __restrict__ Kp,
                                            unsigned short* __restrict__ Vp)
{
    const int tid = threadIdx.x;
    const int bid = blockIdx.x;
    const int b = bid >> 5, t = bid & 31;
    const size_t ibase = (size_t)b * S_LEN * D_HEAD + (size_t)t * KVBLK * D_HEAD;
    unsigned short* ko = Kp + (size_t)bid * TILE_SH;
    unsigned short* vo = Vp + (size_t)bid * TILE_SH;

    #pragma unroll
    for (int c = 0; c < 4; ++c) {
        int i  = c * 256 + tid;
        int k  = i >> 4;
        int d8 = ((i & 15) * 8) ^ ((k & 7) << 3);
        const float* sp = K + ibase + (size_t)k * D_HEAD + d8;
        float4 a = *(const float4*)sp;
        float4 bb = *(const float4*)(sp + 4);
        uint4 u = { pack2(f2bf(a.x),f2bf(a.y)),  pack2(f2bf(a.z),f2bf(a.w)),
                    pack2(f2bf(bb.x),f2bf(bb.y)),pack2(f2bf(bb.z),f2bf(bb.w)) };
        *(uint4*)(ko + i * 8) = u;
    }

    __shared__ unsigned short Vb[KVBLK][D_HEAD + 2];
    {
        const int r  = tid >> 2;
        const int c0 = (tid & 3) * 32;
        const float* sp = V + ibase + (size_t)r * D_HEAD + c0;
        #pragma unroll
        for (int i = 0; i < 8; ++i) {
            float4 x = *(const float4*)(sp + i * 4);
            Vb[r][c0+i*4+0] = f2bf(x.x); Vb[r][c0+i*4+1] = f2bf(x.y);
            Vb[r][c0+i*4+2] = f2bf(x.z); Vb[r][c0+i*4+3] = f2bf(x.w);
        }
    }
    __syncthreads();
    #pragma unroll
    for (int c = 0; c < 4; ++c) {
        int i   = c * 256 + tid;
        int d   = i >> 3;
        int kk0 = ((i & 7) * 8) ^ ((d & 7) << 3);
        unsigned short h[8];
        #pragma unroll
        for (int j = 0; j < 8; ++j) h[j] = Vb[kk0 + j][d];
        uint4 u = { pack2(h[0],h[1]), pack2(h[2],h[3]), pack2(h[4],h[5]), pack2(h[6],h[7]) };
        *(uint4*)(vo + i * 8) = u;
    }
}

// MODE 1: 1024 jobs, bid = o*16 + b (XCD = b%8; 2 batches/XCD). Schedule as
// r11/r15 (4 size-flat rounds, 33 visits/CU). Partials merged by a SEPARATE
// combine kernel (fused merges failed twice: r10/r12).
//
// 2-barrier loop. Hazard ledger:
//   bar1 (top):  all waves past prev PV -> Vlds free for stage_V(t);
//                preceded by per-wave vm0 -> own K(t) issues landed; bar1
//                broadcasts "all K(t) quarters landed".
//   bar2 (mid):  preceded by per-wave vm0 -> own V(t) issues landed; bar2
//                broadcasts "all V(t) quarters landed" AND "all waves done
//                reading Klds (QK^T)" -> stage_K(t+1) safe after bar2.
//   P-write/PV:  wave-private Plds, in-wave ds order; PV reads Vlds (covered
//                by bar2); K(t+1) DMA hides under P-write+PV.
template<int MODE>
__global__ __launch_bounds__(256, 4)
void attn_fwd(const float* __restrict__ Qg, const unsigned short* __restrict__ Kp,
              const unsigned short* __restrict__ Vp, float* __restrict__ Og,
              unsigned short* __restrict__ Po, float* __restrict__ Ml)
{
    constexpr float CSC = 0.12751744f;      // log2(e)/sqrt(128), folded into Q
    const int tid  = threadIdx.x;
    const int lane = tid & 63;
    const int w    = tid >> 6;
    const int bid  = blockIdx.x;

    int b, qb, lo, nt, C = 1, piece = 0, pslot = -1;
    if (MODE == 0) {
        b = bid & 15;
        const int rank = bid >> 4;
        qb = (rank < 16) ? (31 - rank) : (rank - 16);
        lo = 0; nt = qb + 1;
    } else {
        b = bid & 15;
        const int o = bid >> 4, k = o & 15, r = o >> 4;
        if (r <= 1)      { qb = 31 - k; C = (k < 8) ? 3 : 2; piece = r; }
        else if (r == 2) { if (k < 8) { qb = 31 - k; C = 3; piece = 2; }
                           else       { qb = k;      C = 2; piece = 0; } }
        else             { if (k < 8) { qb = k;      C = 1; piece = 0; }
                           else       { qb = k;      C = 2; piece = 1; } }
        const int n = qb + 1, q_ = n / C, rem = n % C;
        lo = piece * q_ + min(piece, rem);
        nt = q_ + (piece < rem ? 1 : 0);
        if (C > 1) pslot = slot_base(b, qb) + piece;
    }
    const int q0w  = qb * QBLK + w * 16;
    const int qc   = lane & 15;
    const int g    = lane >> 4;
    const int qidx = q0w + qc;

    __shared__ __align__(16) unsigned short Klds[TILE_SH];        // 16 KB
    __shared__ __align__(16) unsigned short Vlds[TILE_SH];        // 16 KB
    __shared__ __align__(16) unsigned short Plds[4][16 * KVBLK];  //  8 KB

    const size_t base = (size_t)b * S_LEN * D_HEAD;
    const int tb = b * NKVT;

    auto stage_K = [&](int t) {             // 4 DMA issues/wave
        const unsigned short* ks = Kp + (size_t)(tb + t) * TILE_SH + w * 2048 + lane * 8;
        #pragma unroll
        for (int ii = 0; ii < 4; ++ii) gld16(ks + ii * 512, &Klds[w * 2048 + ii * 512]);
    };
    auto stage_V = [&](int t) {
        const unsigned short* vs = Vp + (size_t)(tb + t) * TILE_SH + w * 2048 + lane * 8;
        #pragma unroll
        for (int ii = 0; ii < 4; ++ii) gld16(vs + ii * 512, &Vlds[w * 2048 + ii * 512]);
    };

    // ---- Q fragments (MFMA B operand), pre-scaled ----
    short8 qf[4];
    {
        const float* qp = Qg + base + (size_t)(q0w + qc) * D_HEAD + g * 8;
        #pragma unroll
        for (int db = 0; db < 4; ++db) {
            float4 x0 = *(const float4*)(qp + db * 32);
            float4 x1 = *(const float4*)(qp + db * 32 + 4);
            float tt[8] = {x0.x, x0.y, x0.z, x0.w, x1.x, x1.y, x1.z, x1.w};
            short8 f;
            #pragma unroll
            for (int jj = 0; jj < 8; ++jj) f[jj] = (short)f2bf(tt[jj] * CSC);
            qf[db] = f;
        }
    }

    f32x4 acc[8] = {};                      // acc[db][r] = O[q=4g+r][d=db*16+qc]
    float m = -1e30f, lsum = 0.f;           // lsum lane-partial until epilogue

    stage_K(lo);                            // K(lo) in flight over Q-frag load

    for (int i = 0; i < nt; ++i) {
        const int t   = lo + i;
        const int kv0 = t * KVBLK;
        const bool more = (i + 1 < nt);

        // bar1: own K(t) landed (vm0) + all waves past prev PV -> Vlds free
        wait_vm<0>();
        barrier();
        stage_V(t);                          // V(t) DMA hides under QK^T+softmax

        const int t16max = min(3, (q0w + 15 - kv0) >> 4);
        const int ksmax  = min(1, (q0w + 15 - kv0) >> 5);

        // ---- swapped QK^T: rows = k, cols = q ----
        f32x4 st[4] = {};
        __builtin_amdgcn_s_setprio(1);
        #pragma unroll
        for (int t16 = 0; t16 < 4; ++t16) {
            if (t16 <= t16max) {
                const int kr = t16 * 16 + qc;
                const int swz = (kr & 7) << 3;
                #pragma unroll
                for (int db = 0; db < 4; ++db) {
                    short8 kf = *(const short8*)&Klds[(kr * 128 + db * 32 + g * 8) ^ swz];
                    st[t16] = __builtin_amdgcn_mfma_f32_16x16x32_bf16(kf, qf[db], st[t16], 0, 0, 0);
                }
            }
        }
        __builtin_amdgcn_s_setprio(0);

        float s[16];
        #pragma unroll
        for (int t16 = 0; t16 < 4; ++t16)
            #pragma unroll
            for (int r = 0; r < 4; ++r)
                s[t16*4+r] = (t16 <= t16max) ? st[t16][r] : -1e30f;

        if (kv0 + KVBLK - 1 > q0w) {         // diagonal: per-lane causal mask
            #pragma unroll
            for (int t16 = 0; t16 < 4; ++t16)
                #pragma unroll
                for (int r = 0; r < 4; ++r)
                    if (kv0 + t16 * 16 + g * 4 + r > qidx) s[t16*4+r] = -1e30f;
        }

        // ---- online softmax, defer-max; no cross-lane ops in common path ----
        float m0 = fmaxf(fmaxf(s[0],s[1]), fmaxf(s[2],s[3]));
        float m1 = fmaxf(fmaxf(s[4],s[5]), fmaxf(s[6],s[7]));
        float m2 = fmaxf(fmaxf(s[8],s[9]), fmaxf(s[10],s[11]));
        float m3 = fmaxf(fmaxf(s[12],s[13]), fmaxf(s[14],s[15]));
        float mx = fmaxf(fmaxf(m0,m1), fmaxf(m2,m3));

        if (__any(mx > m + 8.0f)) {
            mx = fmaxf(mx, __shfl_xor(mx, 16));
            mx = fmaxf(mx, __shfl_xor(mx, 32));
            float mnew = fmaxf(m, mx);
            float alpha = exp2f(m - mnew);
            m = mnew;
            lsum *= alpha;
            float a_o[4];
            #pragma unroll
            for (int r = 0; r < 4; ++r) a_o[r] = __shfl(alpha, g * 4 + r);
            #pragma unroll
            for (int db = 0; db < 8; ++db)
                #pragma unroll
                for (int r = 0; r < 4; ++r) acc[db][r] *= a_o[r];
        }

        float p16[16];
        #pragma unroll
        for (int ii = 0; ii < 16; ++ii) p16[ii] = exp2f(s[ii] - m);
        float r0 = (p16[0]+p16[1]) + (p16[2]+p16[3]);
        float r1 = (p16[4]+p16[5]) + (p16[6]+p16[7]);
        float r2 = (p16[8]+p16[9]) + (p16[10]+p16[11]);
        float r3 = (p16[12]+p16[13]) + (p16[14]+p16[15]);
        lsum += (r0+r1) + (r2+r3);

        // bar2: own V(t) landed (vm0) + all waves done reading Klds
        wait_vm<0>();
        barrier();
        if (more) stage_K(t + 1);            // K DMA hides under P-write + PV

        // ---- P -> wave-private LDS (bf16, swizzled) ----
        const int pswz = (qc & 7) << 3;
        #pragma unroll
        for (int t16 = 0; t16 < 4; ++t16) {
            uint2 uu = { cvtpk(p16[t16*4+0], p16[t16*4+1]), cvtpk(p16[t16*4+2], p16[t16*4+3]) };
            *(uint2*)&Plds[w][(qc * 64 + t16 * 16 + g * 4) ^ pswz] = uu;
        }

        // ---- PV ----
        __builtin_amdgcn_s_setprio(1);
        #pragma unroll
        for (int ks = 0; ks < 2; ++ks) {
            if (ks <= ksmax) {
                short8 pa = *(const short8*)&Plds[w][(qc * 64 + ks * 32 + g * 8) ^ pswz];
                #pragma unroll
                for (int db = 0; db < 8; ++db) {
                    const int d = db * 16 + qc;
                    short8 vf = *(const short8*)&Vlds[(d * 64 + ks * 32 + g * 8) ^ ((d & 7) << 3)];
                    acc[db] = __builtin_amdgcn_mfma_f32_16x16x32_bf16(pa, vf, acc[db], 0, 0, 0);
                }
            }
        }
        __builtin_amdgcn_s_setprio(0);
        // no post-PV barrier: next iteration's bar1 protects Vlds
    }

    // ---- epilogue ----
    lsum += __shfl_xor(lsum, 16);
    lsum += __shfl_xor(lsum, 32);

    if (pslot < 0) {                         // direct write (C==1 or MODE 0)
        float linv = 1.0f / lsum;
        float li[4];
        #pragma unroll
        for (int r = 0; r < 4; ++r) li[r] = __shfl(linv, g * 4 + r);
        #pragma unroll
        for (int db = 0; db < 8; ++db)
            #pragma unroll
            for (int r = 0; r < 4; ++r)
                Og[base + (size_t)(q0w + g * 4 + r) * D_HEAD + db * 16 + qc] = acc[db][r] * li[r];
    } else {                                 // bf16 partial + (m,l)
        unsigned short* po = Po + (size_t)pslot * (QBLK * D_HEAD);
        #pragma unroll
        for (int db = 0; db < 8; ++db)
            #pragma unroll
            for (int r = 0; r < 4; ++r)
                po[(w * 16 + g * 4 + r) * D_HEAD + db * 16 + qc] = f2bf(acc[db][r]);
        if (g == 0) {
            float* ml = Ml + (size_t)pslot * (QBLK * 2);
            ml[(w * 16 + qc) * 2 + 0] = m;
            ml[(w * 16 + qc) * 2 + 1] = lsum;
        }
    }
}

// combine C in {2,3} pieces of each split q-block (qb 8..31); 384 blocks.
__global__ __launch_bounds__(256)
void combine(const unsigned short* __restrict__ Po, const float* __restrict__ Ml,
             float* __restrict__ Og)
{
    const int z   = blockIdx.x;             // j*16 + b  (XCD = b%8)
    const int b   = z & 15;
    const int j   = z >> 4;                 // 0..23
    const int qb  = (j < 16) ? (8 + j) : (24 + (j - 16));
    const int C   = (qb >= 24) ? 3 : 2;
    const int tid = threadIdx.x;
    const int row = tid >> 2;
    const int c0  = (tid & 3) * 32;
    const int sb  = slot_base(b, qb);

    float mm[3], lv[3], M = -1e30f;
    #pragma unroll
    for (int c = 0; c < 3; ++c) {
        if (c < C) {
            const float* ml = Ml + (size_t)(sb + c) * (QBLK * 2);
            mm[c] = ml[row * 2 + 0];
            lv[c] = ml[row * 2 + 1];
            M = fmaxf(M, mm[c]);
        }
    }
    float den = 0.f, wgt[3];
    #pragma unroll
    for (int c = 0; c < 3; ++c) {
        if (c < C) { wgt[c] = exp2f(mm[c] - M); den += wgt[c] * lv[c]; }
    }
    const float rd = 1.0f / den;

    float am[32];
    #pragma unroll
    for (int q = 0; q < 32; ++q) am[q] = 0.f;
    #pragma unroll
    for (int c = 0; c < 3; ++c) {
        if (c < C) {
            const unsigned short* po = Po + (size_t)(sb + c) * (QBLK * D_HEAD) + row * D_HEAD + c0;
            const float wc = wgt[c];
            #pragma unroll
            for (int q = 0; q < 4; ++q) {
                uint4 u = *(const uint4*)(po + q * 8);
                const unsigned short* h = (const unsigned short*)&u;
                #pragma unroll
                for (int e = 0; e < 8; ++e) am[q * 8 + e] += wc * bf2f(h[e]);
            }
        }
    }
    float* op = Og + (size_t)b * S_LEN * D_HEAD + (size_t)(qb * QBLK + row) * D_HEAD + c0;
    #pragma unroll
    for (int q = 0; q < 8; ++q) {
        float4 r = { am[q*4+0] * rd, am[q*4+1] * rd, am[q*4+2] * rd, am[q*4+3] * rd };
        *(float4*)(op + q * 4) = r;
    }
}

extern "C" void kernel_launch(void* const* d_in, const int* in_sizes, int n_in,
                              void* d_out, int out_size, void* d_ws, size_t ws_size,
                              hipStream_t stream) {
    const float* Q = (const float*)d_in[0];
    const float* K = (const float*)d_in[1];
    const float* V = (const float*)d_in[2];
    float* O = (float*)d_out;

    const size_t tile_elems = (size_t)BATCH * NKVT * TILE_SH;       // 4.19M shorts each
    const size_t nslots = (size_t)BATCH * SLOTS_PB;                 // 896
    unsigned short* Kp = (unsigned short*)d_ws;
    unsigned short* Vp = Kp + tile_elems;
    unsigned short* Po = Vp + tile_elems;                           // 896 x 8192 bf16
    float*          Mlp = (float*)(Po + nslots * QBLK * D_HEAD);    // 896 x 128 f32
    const size_t need_bytes = (char*)(Mlp + nslots * QBLK * 2) - (char*)d_ws;

    prep<<<dim3(BATCH * NKVT), dim3(256), 0, stream>>>(K, V, Kp, Vp);
    if (ws_size >= need_bytes) {
        attn_fwd<1><<<dim3(1024), dim3(256), 0, stream>>>(Q, Kp, Vp, O, Po, Mlp);
        combine<<<dim3(24 * BATCH), dim3(256), 0, stream>>>(Po, Mlp, O);
    } else {
        attn_fwd<0><<<dim3(512), dim3(256), 0, stream>>>(Q, Kp, Vp, O, nullptr, nullptr);
    }
}

// Round 24
// 58.046 us; speedup vs baseline: 1.0154x; 1.0032x over previous
//
#include <hip/hip_runtime.h>
#include <math.h>

#define S_LEN  2048
#define D_HEAD 128
#define QBLK   64
#define KVBLK  64
#define BATCH  16
#define NKVT   (S_LEN / KVBLK)     // 32 kv tiles per batch
#define TILE_SH 8192               // shorts per 64x128 tile image (16 KB)
#define SLOTS_PB 56                // partial slots per batch: 16 qb x2 + 8 qb x3

typedef __attribute__((ext_vector_type(4))) float f32x4;
typedef __attribute__((ext_vector_type(8))) short short8;

__device__ __forceinline__ unsigned short f2bf(float x) {
    union { float f; unsigned u; } v; v.f = x;
    unsigned r = v.u + 0x7fffu + ((v.u >> 16) & 1u);
    return (unsigned short)(r >> 16);
}
__device__ __forceinline__ float bf2f(unsigned short h) {
    union { unsigned u; float f; } v; v.u = ((unsigned)h) << 16;
    return v.f;
}
__device__ __forceinline__ unsigned pack2(unsigned short a, unsigned short b) {
    return (unsigned)a | ((unsigned)b << 16);
}
__device__ __forceinline__ unsigned cvtpk(float lo, float hi) {
    unsigned r;
    asm("v_cvt_pk_bf16_f32 %0, %1, %2" : "=v"(r) : "v"(lo), "v"(hi));
    return r;
}
__device__ __forceinline__ void gld16(const void* g, void* l) {
    __builtin_amdgcn_global_load_lds(
        (const __attribute__((address_space(1))) void*)g,
        (__attribute__((address_space(3))) void*)l, 16, 0, 0);
}
template<int N> __device__ __forceinline__ void wait_vm() {
    asm volatile("s_waitcnt vmcnt(%0)" :: "i"(N) : "memory");
}
__device__ __forceinline__ void barrier() {
    __builtin_amdgcn_sched_barrier(0);
    __builtin_amdgcn_s_barrier();
    __builtin_amdgcn_sched_barrier(0);
}
__device__ __forceinline__ int slot_base(int b, int qb) {   // qb >= 8
    return b * SLOTS_PB + ((qb >= 24) ? (32 + (qb - 24) * 3) : ((qb - 8) * 2));
}

// prep: one block per (batch, kv-tile). Emits PRE-SWIZZLED contiguous LDS images.
__global__ __launch_bounds__(256) void prep(const float* __restrict__ K,
                                            const float* __restrict__ V,
                                            unsigned short* __restrict__ Kp,
                                            unsigned short* __restrict__ Vp)
{
    const int tid = threadIdx.x;
    const int bid = blockIdx.x;
    const int b = bid >> 5, t = bid & 31;
    const size_t ibase = (size_t)b * S_LEN * D_HEAD + (size_t)t * KVBLK * D_HEAD;
    unsigned short* ko = Kp + (size_t)bid * TILE_SH;
    unsigned short* vo = Vp + (size_t)bid * TILE_SH;

    #pragma unroll
    for (int c = 0; c < 4; ++c) {
        int i  = c * 256 + tid;
        int k  = i >> 4;
        int d8 = ((i & 15) * 8) ^ ((k & 7) << 3);
        const float* sp = K + ibase + (size_t)k * D_HEAD + d8;
        float4 a = *(const float4*)sp;
        float4 bb = *(const float4*)(sp + 4);
        uint4 u = { pack2(f2bf(a.x),f2bf(a.y)),  pack2(f2bf(a.z),f2bf(a.w)),
                    pack2(f2bf(bb.x),f2bf(bb.y)),pack2(f2bf(bb.z),f2bf(bb.w)) };
        *(uint4*)(ko + i * 8) = u;
    }

    __shared__ unsigned short Vb[KVBLK][D_HEAD + 2];
    {
        const int r  = tid >> 2;
        const int c0 = (tid & 3) * 32;
        const float* sp = V + ibase + (size_t)r * D_HEAD + c0;
        #pragma unroll
        for (int i = 0; i < 8; ++i) {
            float4 x = *(const float4*)(sp + i * 4);
            Vb[r][c0+i*4+0] = f2bf(x.x); Vb[r][c0+i*4+1] = f2bf(x.y);
            Vb[r][c0+i*4+2] = f2bf(x.z); Vb[r][c0+i*4+3] = f2bf(x.w);
        }
    }
    __syncthreads();
    #pragma unroll
    for (int c = 0; c < 4; ++c) {
        int i   = c * 256 + tid;
        int d   = i >> 3;
        int kk0 = ((i & 7) * 8) ^ ((d & 7) << 3);
        unsigned short h[8];
        #pragma unroll
        for (int j = 0; j < 8; ++j) h[j] = Vb[kk0 + j][d];
        uint4 u = { pack2(h[0],h[1]), pack2(h[2],h[3]), pack2(h[4],h[5]), pack2(h[6],h[7]) };
        *(uint4*)(vo + i * 8) = u;
    }
}

// MODE 1: 1024 jobs, bid = o*16 + b (XCD = b%8; 2 batches/XCD). Schedule as
// r11/r15 (4 size-flat rounds, 33 visits/CU). Partials merged by a SEPARATE
// combine kernel (fused merges failed twice: r10/r12).
//
// 2-barrier loop. Hazard ledger:
//   bar1 (top):  all waves past prev PV -> Vlds free for stage_V(t);
//                preceded by per-wave vm0 -> own K(t) issues landed; bar1
//                broadcasts "all K(t) quarters landed".
//   bar2 (mid):  preceded by per-wave vm0 -> own V(t) issues landed; bar2
//                broadcasts "all V(t) quarters landed" AND "all waves done
//                reading Klds (QK^T)" -> stage_K(t+1) safe after bar2.
//   P-write/PV:  wave-private Plds, in-wave ds order; PV reads Vlds (covered
//                by bar2); K(t+1) DMA hides under P-write+PV.
template<int MODE>
__global__ __launch_bounds__(256, 4)
void attn_fwd(const float* __restrict__ Qg, const unsigned short* __restrict__ Kp,
              const unsigned short* __restrict__ Vp, float* __restrict__ Og,
              unsigned short* __restrict__ Po, float* __restrict__ Ml)
{
    constexpr float CSC = 0.12751744f;      // log2(e)/sqrt(128), folded into Q
    const int tid  = threadIdx.x;
    const int lane = tid & 63;
    const int w    = tid >> 6;
    const int bid  = blockIdx.x;

    int b, qb, lo, nt, C = 1, piece = 0, pslot = -1;
    if (MODE == 0) {
        b = bid & 15;
        const int rank = bid >> 4;
        qb = (rank < 16) ? (31 - rank) : (rank - 16);
        lo = 0; nt = qb + 1;
    } else {
        b = bid & 15;
        const int o = bid >> 4, k = o & 15, r = o >> 4;
        if (r <= 1)      { qb = 31 - k; C = (k < 8) ? 3 : 2; piece = r; }
        else if (r == 2) { if (k < 8) { qb = 31 - k; C = 3; piece = 2; }
                           else       { qb = k;      C = 2; piece = 0; } }
        else             { if (k < 8) { qb = k;      C = 1; piece = 0; }
                           else       { qb = k;      C = 2; piece = 1; } }
        const int n = qb + 1, q_ = n / C, rem = n % C;
        lo = piece * q_ + min(piece, rem);
        nt = q_ + (piece < rem ? 1 : 0);
        if (C > 1) pslot = slot_base(b, qb) + piece;
    }
    const int q0w  = qb * QBLK + w * 16;
    const int qc   = lane & 15;
    const int g    = lane >> 4;
    const int qidx = q0w + qc;

    __shared__ __align__(16) unsigned short Klds[TILE_SH];        // 16 KB
    __shared__ __align__(16) unsigned short Vlds[TILE_SH];        // 16 KB
    __shared__ __align__(16) unsigned short Plds[4][16 * KVBLK];  //  8 KB

    const size_t base = (size_t)b * S_LEN * D_HEAD;
    const int tb = b * NKVT;

    auto stage_K = [&](int t) {             // 4 DMA issues/wave
        const unsigned short* ks = Kp + (size_t)(tb + t) * TILE_SH + w * 2048 + lane * 8;
        #pragma unroll
        for (int ii = 0; ii < 4; ++ii) gld16(ks + ii * 512, &Klds[w * 2048 + ii * 512]);
    };
    auto stage_V = [&](int t) {
        const unsigned short* vs = Vp + (size_t)(tb + t) * TILE_SH + w * 2048 + lane * 8;
        #pragma unroll
        for (int ii = 0; ii < 4; ++ii) gld16(vs + ii * 512, &Vlds[w * 2048 + ii * 512]);
    };

    // ---- Q fragments (MFMA B operand), pre-scaled ----
    short8 qf[4];
    {
        const float* qp = Qg + base + (size_t)(q0w + qc) * D_HEAD + g * 8;
        #pragma unroll
        for (int db = 0; db < 4; ++db) {
            float4 x0 = *(const float4*)(qp + db * 32);
            float4 x1 = *(const float4*)(qp + db * 32 + 4);
            float tt[8] = {x0.x, x0.y, x0.z, x0.w, x1.x, x1.y, x1.z, x1.w};
            short8 f;
            #pragma unroll
            for (int jj = 0; jj < 8; ++jj) f[jj] = (short)f2bf(tt[jj] * CSC);
            qf[db] = f;
        }
    }

    f32x4 acc[8] = {};                      // acc[db][r] = O[q=4g+r][d=db*16+qc]
    float m = -1e30f, lsum = 0.f;           // lsum lane-partial until epilogue

    stage_K(lo);                            // K(lo) in flight over Q-frag load

    for (int i = 0; i < nt; ++i) {
        const int t   = lo + i;
        const int kv0 = t * KVBLK;
        const bool more = (i + 1 < nt);

        // bar1: own K(t) landed (vm0) + all waves past prev PV -> Vlds free
        wait_vm<0>();
        barrier();
        stage_V(t);                          // V(t) DMA hides under QK^T+softmax

        const int t16max = min(3, (q0w + 15 - kv0) >> 4);
        const int ksmax  = min(1, (q0w + 15 - kv0) >> 5);

        // ---- swapped QK^T: rows = k, cols = q ----
        f32x4 st[4] = {};
        __builtin_amdgcn_s_setprio(1);
        #pragma unroll
        for (int t16 = 0; t16 < 4; ++t16) {
            if (t16 <= t16max) {
                const int kr = t16 * 16 + qc;
                const int swz = (kr & 7) << 3;
                #pragma unroll
                for (int db = 0; db < 4; ++db) {
                    short8 kf = *(const short8*)&Klds[(kr * 128 + db * 32 + g * 8) ^ swz];
                    st[t16] = __builtin_amdgcn_mfma_f32_16x16x32_bf16(kf, qf[db], st[t16], 0, 0, 0);
                }
            }
        }
        __builtin_amdgcn_s_setprio(0);

        float s[16];
        #pragma unroll
        for (int t16 = 0; t16 < 4; ++t16)
            #pragma unroll
            for (int r = 0; r < 4; ++r)
                s[t16*4+r] = (t16 <= t16max) ? st[t16][r] : -1e30f;

        if (kv0 + KVBLK - 1 > q0w) {         // diagonal: per-lane causal mask
            #pragma unroll
            for (int t16 = 0; t16 < 4; ++t16)
                #pragma unroll
                for (int r = 0; r < 4; ++r)
                    if (kv0 + t16 * 16 + g * 4 + r > qidx) s[t16*4+r] = -1e30f;
        }

        // ---- online softmax, defer-max; no cross-lane ops in common path ----
        float m0 = fmaxf(fmaxf(s[0],s[1]), fmaxf(s[2],s[3]));
        float m1 = fmaxf(fmaxf(s[4],s[5]), fmaxf(s[6],s[7]));
        float m2 = fmaxf(fmaxf(s[8],s[9]), fmaxf(s[10],s[11]));
        float m3 = fmaxf(fmaxf(s[12],s[13]), fmaxf(s[14],s[15]));
        float mx = fmaxf(fmaxf(m0,m1), fmaxf(m2,m3));

        if (__any(mx > m + 8.0f)) {
            mx = fmaxf(mx, __shfl_xor(mx, 16));
            mx = fmaxf(mx, __shfl_xor(mx, 32));
            float mnew = fmaxf(m, mx);
            float alpha = exp2f(m - mnew);
            m = mnew;
            lsum *= alpha;
            float a_o[4];
            #pragma unroll
            for (int r = 0; r < 4; ++r) a_o[r] = __shfl(alpha, g * 4 + r);
            #pragma unroll
            for (int db = 0; db < 8; ++db)
                #pragma unroll
                for (int r = 0; r < 4; ++r) acc[db][r] *= a_o[r];
        }

        float p16[16];
        #pragma unroll
        for (int ii = 0; ii < 16; ++ii) p16[ii] = exp2f(s[ii] - m);
        float r0 = (p16[0]+p16[1]) + (p16[2]+p16[3]);
        float r1 = (p16[4]+p16[5]) + (p16[6]+p16[7]);
        float r2 = (p16[8]+p16[9]) + (p16[10]+p16[11]);
        float r3 = (p16[12]+p16[13]) + (p16[14]+p16[15]);
        lsum += (r0+r1) + (r2+r3);

        // bar2: own V(t) landed (vm0) + all waves done reading Klds
        wait_vm<0>();
        barrier();
        if (more) stage_K(t + 1);            // K DMA hides under P-write + PV

        // ---- P -> wave-private LDS (bf16, swizzled) ----
        const int pswz = (qc & 7) << 3;
        #pragma unroll
        for (int t16 = 0; t16 < 4; ++t16) {
            uint2 uu = { cvtpk(p16[t16*4+0], p16[t16*4+1]), cvtpk(p16[t16*4+2], p16[t16*4+3]) };
            *(uint2*)&Plds[w][(qc * 64 + t16 * 16 + g * 4) ^ pswz] = uu;
        }

        // ---- PV ----
        __builtin_amdgcn_s_setprio(1);
        #pragma unroll
        for (int ks = 0; ks < 2; ++ks) {
            if (ks <= ksmax) {
                short8 pa = *(const short8*)&Plds[w][(qc * 64 + ks * 32 + g * 8) ^ pswz];
                #pragma unroll
                for (int db = 0; db < 8; ++db) {
                    const int d = db * 16 + qc;
                    short8 vf = *(const short8*)&Vlds[(d * 64 + ks * 32 + g * 8) ^ ((d & 7) << 3)];
                    acc[db] = __builtin_amdgcn_mfma_f32_16x16x32_bf16(pa, vf, acc[db], 0, 0, 0);
                }
            }
        }
        __builtin_amdgcn_s_setprio(0);
        // no post-PV barrier: next iteration's bar1 protects Vlds
    }

    // ---- epilogue ----
    lsum += __shfl_xor(lsum, 16);
    lsum += __shfl_xor(lsum, 32);

    if (pslot < 0) {                         // direct write (C==1 or MODE 0)
        float linv = 1.0f / lsum;
        float li[4];
        #pragma unroll
        for (int r = 0; r < 4; ++r) li[r] = __shfl(linv, g * 4 + r);
        #pragma unroll
        for (int db = 0; db < 8; ++db)
            #pragma unroll
            for (int r = 0; r < 4; ++r)
                Og[base + (size_t)(q0w + g * 4 + r) * D_HEAD + db * 16 + qc] = acc[db][r] * li[r];
    } else {                                 // bf16 partial + (m,l)
        unsigned short* po = Po + (size_t)pslot * (QBLK * D_HEAD);
        #pragma unroll
        for (int db = 0; db < 8; ++db)
            #pragma unroll
            for (int r = 0; r < 4; ++r)
                po[(w * 16 + g * 4 + r) * D_HEAD + db * 16 + qc] = f2bf(acc[db][r]);
        if (g == 0) {
            float* ml = Ml + (size_t)pslot * (QBLK * 2);
            ml[(w * 16 + qc) * 2 + 0] = m;
            ml[(w * 16 + qc) * 2 + 1] = lsum;
        }
    }
}

// combine C in {2,3} pieces of each split q-block (qb 8..31); 384 blocks.
__global__ __launch_bounds__(256)
void combine(const unsigned short* __restrict__ Po, const float* __restrict__ Ml,
             float* __restrict__ Og)
{
    const int z   = blockIdx.x;             // j*16 + b  (XCD = b%8)
    const int b   = z & 15;
    const int j   = z >> 4;                 // 0..23
    const int qb  = (j < 16) ? (8 + j) : (24 + (j - 16));
    const int C   = (qb >= 24) ? 3 : 2;
    const int tid = threadIdx.x;
    const int row = tid >> 2;
    const int c0  = (tid & 3) * 32;
    const int sb  = slot_base(b, qb);

    float mm[3], lv[3], M = -1e30f;
    #pragma unroll
    for (int c = 0; c < 3; ++c) {
        if (c < C) {
            const float* ml = Ml + (size_t)(sb + c) * (QBLK * 2);
            mm[c] = ml[row * 2 + 0];
            lv[c] = ml[row * 2 + 1];
            M = fmaxf(M, mm[c]);
        }
    }
    float den = 0.f, wgt[3];
    #pragma unroll
    for (int c = 0; c < 3; ++c) {
        if (c < C) { wgt[c] = exp2f(mm[c] - M); den += wgt[c] * lv[c]; }
    }
    const float rd = 1.0f / den;

    float am[32];
    #pragma unroll
    for (int q = 0; q < 32; ++q) am[q] = 0.f;
    #pragma unroll
    for (int c = 0; c < 3; ++c) {
        if (c < C) {
            const unsigned short* po = Po + (size_t)(sb + c) * (QBLK * D_HEAD) + row * D_HEAD + c0;
            const float wc = wgt[c];
            #pragma unroll
            for (int q = 0; q < 4; ++q) {
                uint4 u = *(const uint4*)(po + q * 8);
                const unsigned short* h = (const unsigned short*)&u;
                #pragma unroll
                for (int e = 0; e < 8; ++e) am[q * 8 + e] += wc * bf2f(h[e]);
            }
        }
    }
    float* op = Og + (size_t)b * S_LEN * D_HEAD + (size_t)(qb * QBLK + row) * D_HEAD + c0;
    #pragma unroll
    for (int q = 0; q < 8; ++q) {
        float4 r = { am[q*4+0] * rd, am[q*4+1] * rd, am[q*4+2] * rd, am[q*4+3] * rd };
        *(float4*)(op + q * 4) = r;
    }
}

extern "C" void kernel_launch(void* const* d_in, const int* in_sizes, int n_in,
                              void* d_out, int out_size, void* d_ws, size_t ws_size,
                              hipStream_t stream) {
    const float* Q = (const float*)d_in[0];
    const float* K = (const float*)d_in[1];
    const float* V = (const float*)d_in[2];
    float* O = (float*)d_out;

    const size_t tile_elems = (size_t)BATCH * NKVT * TILE_SH;       // 4.19M shorts each
    const size_t nslots = (size_t)BATCH * SLOTS_PB;                 // 896
    unsigned short* Kp = (unsigned short*)d_ws;
    unsigned short* Vp = Kp + tile_elems;
    unsigned short* Po = Vp + tile_elems;                           // 896 x 8192 bf16
    float*          Mlp = (float*)(Po + nslots * QBLK * D_HEAD);    // 896 x 128 f32
    const size_t need_bytes = (char*)(Mlp + nslots * QBLK * 2) - (char*)d_ws;

    prep<<<dim3(BATCH * NKVT), dim3(256), 0, stream>>>(K, V, Kp, Vp);
    if (ws_size >= need_bytes) {
        attn_fwd<1><<<dim3(1024), dim3(256), 0, stream>>>(Q, Kp, Vp, O, Po, Mlp);
        combine<<<dim3(24 * BATCH), dim3(256), 0, stream>>>(Po, Mlp, O);
    } else {
        attn_fwd<0><<<dim3(512), dim3(256), 0, stream>>>(Q, Kp, Vp, O, nullptr, nullptr);
    }
}